// Round 1
// 235.869 us; speedup vs baseline: 1.0146x; 1.0146x over previous
//
#include <hip/hip_runtime.h>

typedef __bf16 bf16_t;
typedef __bf16 bf16x2 __attribute__((ext_vector_type(2)));
typedef __bf16 bf16x4 __attribute__((ext_vector_type(4)));
typedef __bf16 bf16x8 __attribute__((ext_vector_type(8)));
typedef float f32x4 __attribute__((ext_vector_type(4)));
typedef unsigned int u32x4 __attribute__((ext_vector_type(4)));

#define MFMA16(a, b, c) __builtin_amdgcn_mfma_f32_16x16x32_bf16(a, b, c, 0, 0, 0)
#define LOG2E 1.4426950408889634f
#define SHIFT 16.0f

// async global -> LDS, 16B per lane (LDS dest = wave-uniform base + lane*16)
#define GLL(g, l)                                                      \
  __builtin_amdgcn_global_load_lds(                                    \
      (const __attribute__((address_space(1))) void*)(g),              \
      (__attribute__((address_space(3))) void*)(l), 16, 0, 0)

// raw barrier: wait only the OLDEST in-flight GLLs (newest stay in flight),
// then s_barrier WITHOUT the compiler's vmcnt(0) drain.
#define WAIT_BARRIER_V4() asm volatile("s_waitcnt vmcnt(4)\n\ts_barrier" ::: "memory")
#define WAIT_BARRIER_V6() asm volatile("s_waitcnt vmcnt(6)\n\ts_barrier" ::: "memory")

static constexpr int NB = 2;
static constexpr int SEQ = 4096;
static constexpr int DM = 512;
static constexpr int NH = 8;
static constexpr int HD = 64;
static constexpr int M_ROWS = NB * SEQ;  // 8192

// ---------------------------------------------------------------------------
// Weights fp32 -> bf16
// ---------------------------------------------------------------------------
__global__ __launch_bounds__(256) void cvt_w_kernel(
    const float* __restrict__ w0, const float* __restrict__ w1,
    const float* __restrict__ w2, const float* __restrict__ w3,
    bf16_t* __restrict__ out) {
  const float* src = (blockIdx.y == 0) ? w0 : (blockIdx.y == 1) ? w1
                   : (blockIdx.y == 2) ? w2 : w3;
  int i = (blockIdx.x * 256 + threadIdx.x) * 4;
  float4 v = *(const float4*)(src + i);
  bf16_t* o = out + blockIdx.y * (DM * DM) + i;
  o[0] = (bf16_t)v.x; o[1] = (bf16_t)v.y; o[2] = (bf16_t)v.z; o[3] = (bf16_t)v.w;
}

// ---------------------------------------------------------------------------
// Inputs q,k,v fp32 -> bf16 (fused)
// ---------------------------------------------------------------------------
__global__ __launch_bounds__(256) void cvt_x_kernel(
    const float* __restrict__ q, const float* __restrict__ k,
    const float* __restrict__ v, bf16_t* __restrict__ out) {
  const float* src = (blockIdx.y == 0) ? q : (blockIdx.y == 1) ? k : v;
  bf16_t* dst = out + (size_t)blockIdx.y * (M_ROWS * DM);
  int i = (blockIdx.x * 256 + threadIdx.x) * 8;
  float4 a = *(const float4*)(src + i);
  float4 b = *(const float4*)(src + i + 4);
  bf16x8 o;
  o[0] = (bf16_t)a.x; o[1] = (bf16_t)a.y; o[2] = (bf16_t)a.z; o[3] = (bf16_t)a.w;
  o[4] = (bf16_t)b.x; o[5] = (bf16_t)b.y; o[6] = (bf16_t)b.z; o[7] = (bf16_t)b.w;
  *(bf16x8*)(dst + i) = o;
}

// ---------------------------------------------------------------------------
// GEMM v4: Out = (X @ W^T + bias) * scale. Tile 64x128, BK=64, 3-stage LDS
// pipeline with raw-barrier async: per K-step wait only the oldest 6 GLLs
// (vmcnt(6)), raw s_barrier, issue step ks+2 into the buffer freed by ks-1,
// compute step ks. XOR-swizzled LDS (16B chunks, phys = ch ^ (row&7)).
// omode 0: bf16 [bh][s][64]; 1: bf16 [bh][d][s]; 2: fp32 [m][512].
// ---------------------------------------------------------------------------
__device__ __forceinline__ void gemm_body64(
    const bf16_t* __restrict__ X, const bf16_t* __restrict__ Wm,
    const float* __restrict__ bias, void* __restrict__ Out,
    int omode, float scale) {
  __shared__ bf16_t Asm[3][64 * 64];
  __shared__ bf16_t Bsm[3][128 * 64];

  const int tid = threadIdx.x;
  const int w = tid >> 6;
  const int lane = tid & 63;
  const int quad = lane >> 4, l15 = lane & 15;
  const int l8 = lane >> 3;
  const int swcol = ((lane & 7) ^ l8) * 8;  // swizzled source col (elems)
  const int m0 = blockIdx.x * 64;
  const int n0 = blockIdx.y * 128;
  const int moff = (w & 1) * 32;
  const int noff = (w >> 1) * 64;

  f32x4 acc[2][4];
#pragma unroll
  for (int mb = 0; mb < 2; mb++)
#pragma unroll
    for (int nb = 0; nb < 4; nb++) { acc[mb][nb][0] = 0.f; acc[mb][nb][1] = 0.f; acc[mb][nb][2] = 0.f; acc[mb][nb][3] = 0.f; }

  // stage K-step ks into LDS buffer bufi (6 GLLs per thread: 4 B + 2 A)
  auto stage = [&](int ks, int bufi) {
    const int k0 = ks * 64;
#pragma unroll
    for (int j = 0; j < 4; j++) {
      const int row = j * 32 + w * 8 + l8;
      GLL(Wm + (size_t)(n0 + row) * DM + k0 + swcol, &Bsm[bufi][(j * 256 + w * 64) * 8]);
    }
#pragma unroll
    for (int j = 0; j < 2; j++) {
      const int row = j * 32 + w * 8 + l8;
      GLL(X + (size_t)(m0 + row) * DM + k0 + swcol, &Asm[bufi][(j * 256 + w * 64) * 8]);
    }
  };

  stage(0, 0);
  stage(1, 1);

  for (int ks = 0; ks < 8; ks++) {
    WAIT_BARRIER_V6();             // step-ks tile landed everywhere; buffer
                                   // (ks-1)%3 free for reuse
    const int tn = (ks + 2 < 8) ? ks + 2 : 7;   // dummy re-issue keeps counts uniform
    stage(tn, (ks + 2) % 3);
    const int p = ks % 3;

#pragma unroll
    for (int kd = 0; kd < 2; kd++) {
      const int fch = (((kd << 2) + quad) ^ (l15 & 7)) << 3;
      bf16x8 bfr[4];
#pragma unroll
      for (int nb = 0; nb < 4; nb++)
        bfr[nb] = *(const bf16x8*)&Bsm[p][(noff + nb * 16 + l15) * 64 + fch];
#pragma unroll
      for (int mb = 0; mb < 2; mb++) {
        bf16x8 a = *(const bf16x8*)&Asm[p][(moff + mb * 16 + l15) * 64 + fch];
#pragma unroll
        for (int nb = 0; nb < 4; nb++) acc[mb][nb] = MFMA16(a, bfr[nb], acc[mb][nb]);
      }
    }
  }

  // ---- epilogue ----
#pragma unroll
  for (int nb = 0; nb < 4; nb++) {
    const int n = n0 + noff + nb * 16 + l15;
    const float bn = bias[n];
    const int h = n >> 6, dd = n & 63;
#pragma unroll
    for (int mb = 0; mb < 2; mb++) {
      const int mbase = m0 + moff + mb * 16 + quad * 4;
      const int bb = mbase >> 12, s = mbase & 4095;
      if (omode == 0) {
#pragma unroll
        for (int r = 0; r < 4; r++) {
          const float val = (acc[mb][nb][r] + bn) * scale;
          ((bf16_t*)Out)[(size_t)((bb * NH + h) * SEQ + s + r) * HD + dd] = (bf16_t)val;
        }
      } else if (omode == 1) {
        bf16x4 pk;
#pragma unroll
        for (int r = 0; r < 4; r++) pk[r] = (bf16_t)(acc[mb][nb][r] + bn);
        *(bf16x4*)&((bf16_t*)Out)[(((size_t)(bb * NH + h) * HD + dd) << 12) + s] = pk;
      } else {
#pragma unroll
        for (int r = 0; r < 4; r++)
          ((float*)Out)[(size_t)(mbase + r) * DM + n] = acc[mb][nb][r] + bn;
      }
    }
  }
}

// Fused QKV projection (bf16 inputs). Grid (128,4,3).
__global__ __launch_bounds__(256, 2) void qkv_kernel(
    const bf16_t* __restrict__ Xall, const bf16_t* __restrict__ Wall,
    const float* __restrict__ bq, const float* __restrict__ bk,
    const float* __restrict__ bv, bf16_t* __restrict__ Qb,
    bf16_t* __restrict__ Kb, bf16_t* __restrict__ Vb, float qscale) {
  const int z = blockIdx.z;
  const bf16_t* X = Xall + (size_t)z * (M_ROWS * DM);
  const float* bias = (z == 0) ? bq : (z == 1) ? bk : bv;
  bf16_t* Out = (z == 0) ? Qb : (z == 1) ? Kb : Vb;
  gemm_body64(X, Wall + (size_t)z * DM * DM, bias, Out,
              (z == 2) ? 1 : 0, (z == 0) ? qscale : 1.0f);
}

// Output projection. Grid (128,4).
__global__ __launch_bounds__(256, 2) void oproj_kernel(
    const bf16_t* __restrict__ X, const bf16_t* __restrict__ Wm,
    const float* __restrict__ bias, float* __restrict__ Out) {
  gemm_body64(X, Wm, bias, Out, 2, 1.0f);
}

// ---------------------------------------------------------------------------
// Flash attention v6: 3-stage K/V LDS pipeline with raw-barrier async, PLUS
// in-register P redistribution (T12): after swapped QK^T, lane(quad,l15)
// holds P[k=16kb+4q+r][q=l15]; PV needs P[k=32kc+8q+j][q=l15]. The permute
// moves data only between lanes {l15, l15+16, +32, +48}:
//   u[kb][i] = cvt_pk_bf16(e[4kb+2i], e[4kb+2i+1])
//   (w0,w2) = permlane16_swap(permlane32_swap(u[2kc][0], u[2kc+1][0]))
//   (w1,w3) = permlane16_swap(permlane32_swap(u[2kc][1], u[2kc+1][1]))
// This removes the Pt LDS round-trip (8 ds_write_b64 + 4 ds_read_b128 per
// wave-tile + its lgkm waits + its bank conflicts) and drops LDS 64->48KB.
// s_setprio(1) wraps the two MFMA clusters (T5).
// 32 q/wave, 128 q/block. Grid (32,16).
// ---------------------------------------------------------------------------
__global__ __launch_bounds__(256, 2) void attn_kernel(
    const bf16_t* __restrict__ Qb, const bf16_t* __restrict__ Kb,
    const bf16_t* __restrict__ Vb, const float* __restrict__ rel_pos,
    bf16_t* __restrict__ attn_out) {
  __shared__ bf16_t Kt[3][64 * 64];    // swizzled [kk][d], 3-stage
  __shared__ bf16_t Vt[3][64 * 64];    // swizzled [d][kk], 3-stage

  const int tid = threadIdx.x;
  const int w = tid >> 6;
  const int lane = tid & 63;
  const int quad = lane >> 4, l15 = lane & 15;
  const int bh = blockIdx.y;
  const int b = bh >> 3, h = bh & 7;
  const int qlo = blockIdx.x * 128 + w * 32;

  const float rb0 = rel_pos[h * 5 + 0] * LOG2E;
  const float rb1 = rel_pos[h * 5 + 1] * LOG2E;
  const float rb2 = rel_pos[h * 5 + 2] * LOG2E;
  const float rb3 = rel_pos[h * 5 + 3] * LOG2E;
  const float rb4 = rel_pos[h * 5 + 4] * LOG2E;

  // Q fragments (B-operand): two q-groups of 16
  bf16x8 qf[2][2];
#pragma unroll
  for (int mb = 0; mb < 2; mb++)
#pragma unroll
    for (int kd = 0; kd < 2; kd++)
      qf[mb][kd] = *(const bf16x8*)(Qb + (size_t)(bh * SEQ + qlo + mb * 16 + l15) * HD + kd * 32 + 8 * quad);

  f32x4 o[2][4];
#pragma unroll
  for (int mb = 0; mb < 2; mb++)
#pragma unroll
    for (int db = 0; db < 4; db++) { o[mb][db][0] = 0.f; o[mb][db][1] = 0.f; o[mb][db][2] = 0.f; o[mb][db][3] = 0.f; }
  f32x4 l4[2];
  l4[0][0] = 0.f; l4[0][1] = 0.f; l4[0][2] = 0.f; l4[0][3] = 0.f;
  l4[1][0] = 0.f; l4[1][1] = 0.f; l4[1][2] = 0.f; l4[1][3] = 0.f;

  bf16x8 ones;
#pragma unroll
  for (int i = 0; i < 8; i++) ones[i] = (bf16_t)1.0f;

  // --- staging addresses (swizzled): phys chunk = logical ^ (row&7)
  const int srow = (w << 4) + (lane >> 3);
  const int scol = (((lane & 7) ^ (lane >> 3)) << 3);
  const bf16_t* kg0 = Kb + ((size_t)(bh * SEQ + srow) << 6) + scol;
  const bf16_t* vg0 = Vb + (((size_t)(bh * HD + srow)) << 12) + scol;
  const int ldst = (w << 10);  // wave's LDS dest (elems)

  // --- fragment read bases (swizzled)
  const int sw = l15 & 7;
  const int kfo0 = (l15 << 6) + ((quad ^ sw) << 3);
  const int kfo1 = (l15 << 6) + (((quad + 4) ^ sw) << 3);

  auto stage = [&](int t, int bufi) {
    GLL(kg0 + ((size_t)t << 12), &Kt[bufi][ldst]);
    GLL(kg0 + ((size_t)t << 12) + (8 << 6), &Kt[bufi][ldst + 512]);
    GLL(vg0 + (t << 6), &Vt[bufi][ldst]);
    GLL(vg0 + (t << 6) + (8 << 12), &Vt[bufi][ldst + 512]);
  };

  stage(0, 0);
  stage(1, 1);

  for (int t = 0; t < 64; t++) {
    WAIT_BARRIER_V4();             // tile t landed everywhere; buffer (t-1)%3 free
    const int tg = (t + 2 < 64) ? t + 2 : 63;
    stage(tg, (t + 2) % 3);
    const int p = t % 3;
    const int kk0 = t * 64;

    // ---- tile class: fold bias const + fixed shift into acc init ----
    float cini;
    bool nearband = false;
    if (kk0 >= qlo + 33) {
      cini = rb4 - SHIFT;
    } else if (kk0 + 63 <= qlo - 2) {
      cini = rb0 - SHIFT;
    } else {
      cini = -SHIFT;
      nearband = true;
    }

    // ---- S^T = K·Q^T ----
    f32x4 s[2][4];
#pragma unroll
    for (int mb = 0; mb < 2; mb++)
#pragma unroll
      for (int kb = 0; kb < 4; kb++) { s[mb][kb][0] = cini; s[mb][kb][1] = cini; s[mb][kb][2] = cini; s[mb][kb][3] = cini; }
    __builtin_amdgcn_s_setprio(1);
#pragma unroll
    for (int kb = 0; kb < 4; kb++) {
      bf16x8 kA0 = *(const bf16x8*)&Kt[p][kfo0 + (kb << 10)];
      bf16x8 kA1 = *(const bf16x8*)&Kt[p][kfo1 + (kb << 10)];
      s[0][kb] = MFMA16(kA0, qf[0][0], s[0][kb]);
      s[0][kb] = MFMA16(kA1, qf[0][1], s[0][kb]);
      s[1][kb] = MFMA16(kA0, qf[1][0], s[1][kb]);
      s[1][kb] = MFMA16(kA1, qf[1][1], s[1][kb]);
    }
    __builtin_amdgcn_s_setprio(0);

    if (nearband) {
#pragma unroll
      for (int mb = 0; mb < 2; mb++) {
        const int qg = qlo + mb * 16 + l15;
#pragma unroll
        for (int kb = 0; kb < 4; kb++)
#pragma unroll
          for (int r = 0; r < 4; r++) {
            int dl = kk0 + kb * 16 + quad * 4 + r - qg;
            float bias = dl <= -2 ? rb0
                       : (dl >= 2 ? rb4
                       : (dl == -1 ? rb1 : (dl == 0 ? rb2 : rb3)));
            s[mb][kb][r] += bias;
          }
      }
    }

    // ---- p = exp2(s) -> bf16 pack -> in-register redistribution ----
    bf16x8 pf[2][2];
#pragma unroll
    for (int mb = 0; mb < 2; mb++) {
      unsigned int u[4][2];
#pragma unroll
      for (int kb = 0; kb < 4; kb++) {
        bf16x2 p0, p1;
        p0[0] = (bf16_t)__builtin_amdgcn_exp2f(s[mb][kb][0]);
        p0[1] = (bf16_t)__builtin_amdgcn_exp2f(s[mb][kb][1]);
        p1[0] = (bf16_t)__builtin_amdgcn_exp2f(s[mb][kb][2]);
        p1[1] = (bf16_t)__builtin_amdgcn_exp2f(s[mb][kb][3]);
        u[kb][0] = __builtin_bit_cast(unsigned int, p0);
        u[kb][1] = __builtin_bit_cast(unsigned int, p1);
      }
#pragma unroll
      for (int kc = 0; kc < 2; kc++) {
        unsigned int a0 = u[2 * kc][0], b0 = u[2 * kc + 1][0];
        unsigned int a1 = u[2 * kc][1], b1 = u[2 * kc + 1][1];
        asm("v_permlane32_swap_b32 %0, %1" : "+v"(a0), "+v"(b0));
        asm("v_permlane32_swap_b32 %0, %1" : "+v"(a1), "+v"(b1));
        asm("v_permlane16_swap_b32 %0, %1" : "+v"(a0), "+v"(b0));
        asm("v_permlane16_swap_b32 %0, %1" : "+v"(a1), "+v"(b1));
        u32x4 pk; pk[0] = a0; pk[1] = a1; pk[2] = b0; pk[3] = b1;
        pf[mb][kc] = __builtin_bit_cast(bf16x8, pk);
      }
    }

    // ---- l via ones-MFMA, O^T += V^T·P^T ----
    __builtin_amdgcn_s_setprio(1);
    l4[0] = MFMA16(ones, pf[0][0], l4[0]);
    l4[0] = MFMA16(ones, pf[0][1], l4[0]);
    l4[1] = MFMA16(ones, pf[1][0], l4[1]);
    l4[1] = MFMA16(ones, pf[1][1], l4[1]);

#pragma unroll
    for (int db = 0; db < 4; db++) {
      bf16x8 vA0 = *(const bf16x8*)&Vt[p][kfo0 + (db << 10)];
      bf16x8 vA1 = *(const bf16x8*)&Vt[p][kfo1 + (db << 10)];
      o[0][db] = MFMA16(vA0, pf[0][0], o[0][db]);
      o[0][db] = MFMA16(vA1, pf[0][1], o[0][db]);
      o[1][db] = MFMA16(vA0, pf[1][0], o[1][db]);
      o[1][db] = MFMA16(vA1, pf[1][1], o[1][db]);
    }
    __builtin_amdgcn_s_setprio(0);
  }

  // ---- epilogue: O^T / l ----
#pragma unroll
  for (int mb = 0; mb < 2; mb++) {
    const float inv = 1.0f / l4[mb][0];
    const int qg = qlo + mb * 16 + l15;
#pragma unroll
    for (int db = 0; db < 4; db++) {
      bf16x4 pk;
#pragma unroll
      for (int r = 0; r < 4; r++) pk[r] = (bf16_t)(o[mb][db][r] * inv);
      *(bf16x4*)(attn_out + (size_t)(b * SEQ + qg) * DM + h * HD + db * 16 + quad * 4) = pk;
    }
  }
}

// ---------------------------------------------------------------------------
extern "C" void kernel_launch(void* const* d_in, const int* in_sizes, int n_in,
                              void* d_out, int out_size, void* d_ws, size_t ws_size,
                              hipStream_t stream) {
  const float* q   = (const float*)d_in[0];
  const float* k   = (const float*)d_in[1];
  const float* v   = (const float*)d_in[2];
  const float* Wq  = (const float*)d_in[3];
  const float* bq  = (const float*)d_in[4];
  const float* Wk  = (const float*)d_in[5];
  const float* bk  = (const float*)d_in[6];
  const float* Wv  = (const float*)d_in[7];
  const float* bv  = (const float*)d_in[8];
  const float* Wo  = (const float*)d_in[9];
  const float* bo  = (const float*)d_in[10];
  const float* rel = (const float*)d_in[11];

  char* ws = (char*)d_ws;
  bf16_t* Wbf  = (bf16_t*)ws;                               // 2MB (4 matrices)
  bf16_t* Xb   = (bf16_t*)(ws + (size_t)(2  << 20));        // 24MB bf16 q,k,v
  bf16_t* Qbuf = (bf16_t*)(ws + (size_t)(26 << 20));        // 8MB [bh][s][64]
  bf16_t* Kbuf = (bf16_t*)(ws + (size_t)(34 << 20));        // 8MB [bh][s][64]
  bf16_t* Vbuf = (bf16_t*)(ws + (size_t)(42 << 20));        // 8MB [bh][d][s]
  bf16_t* Abuf = (bf16_t*)(ws + (size_t)(2  << 20));        // alias Xb (dead after qkv)

  cvt_w_kernel<<<dim3(256, 4), 256, 0, stream>>>(Wq, Wk, Wv, Wo, Wbf);
  cvt_x_kernel<<<dim3(2048, 3), 256, 0, stream>>>(q, k, v, Xb);

  const float qscale = LOG2E / 8.0f;  // fold 1/sqrt(64) + exp2 domain
  qkv_kernel<<<dim3(128, 4, 3), 256, 0, stream>>>(
      Xb, Wbf, bq, bk, bv, Qbuf, Kbuf, Vbuf, qscale);

  attn_kernel<<<dim3(32, 16), 256, 0, stream>>>(Qbuf, Kbuf, Vbuf, rel, Abuf);

  oproj_kernel<<<dim3(128, 4), 256, 0, stream>>>(Abuf, Wbf + 3 * DM * DM, bo, (float*)d_out);
}

// Round 2
// 232.694 us; speedup vs baseline: 1.0285x; 1.0136x over previous
//
#include <hip/hip_runtime.h>

typedef __bf16 bf16_t;
typedef __bf16 bf16x2 __attribute__((ext_vector_type(2)));
typedef __bf16 bf16x4 __attribute__((ext_vector_type(4)));
typedef __bf16 bf16x8 __attribute__((ext_vector_type(8)));
typedef float f32x4 __attribute__((ext_vector_type(4)));
typedef unsigned int u32x4 __attribute__((ext_vector_type(4)));

#define MFMA16(a, b, c) __builtin_amdgcn_mfma_f32_16x16x32_bf16(a, b, c, 0, 0, 0)
#define LOG2E 1.4426950408889634f
#define SHIFT 16.0f

// async global -> LDS, 16B per lane (LDS dest = wave-uniform base + lane*16)
#define GLL(g, l)                                                      \
  __builtin_amdgcn_global_load_lds(                                    \
      (const __attribute__((address_space(1))) void*)(g),              \
      (__attribute__((address_space(3))) void*)(l), 16, 0, 0)

// raw barrier: wait only the OLDEST in-flight GLLs (newest stay in flight),
// then s_barrier WITHOUT the compiler's vmcnt(0) drain.
#define WAIT_BARRIER_V4() asm volatile("s_waitcnt vmcnt(4)\n\ts_barrier" ::: "memory")
#define WAIT_BARRIER_V6() asm volatile("s_waitcnt vmcnt(6)\n\ts_barrier" ::: "memory")
#define WAIT_BARRIER_V8() asm volatile("s_waitcnt vmcnt(8)\n\ts_barrier" ::: "memory")

static constexpr int NB = 2;
static constexpr int SEQ = 4096;
static constexpr int DM = 512;
static constexpr int NH = 8;
static constexpr int HD = 64;
static constexpr int M_ROWS = NB * SEQ;  // 8192

// ---------------------------------------------------------------------------
// Weights fp32 -> bf16
// ---------------------------------------------------------------------------
__global__ __launch_bounds__(256) void cvt_w_kernel(
    const float* __restrict__ w0, const float* __restrict__ w1,
    const float* __restrict__ w2, const float* __restrict__ w3,
    bf16_t* __restrict__ out) {
  const float* src = (blockIdx.y == 0) ? w0 : (blockIdx.y == 1) ? w1
                   : (blockIdx.y == 2) ? w2 : w3;
  int i = (blockIdx.x * 256 + threadIdx.x) * 4;
  float4 v = *(const float4*)(src + i);
  bf16_t* o = out + blockIdx.y * (DM * DM) + i;
  o[0] = (bf16_t)v.x; o[1] = (bf16_t)v.y; o[2] = (bf16_t)v.z; o[3] = (bf16_t)v.w;
}

// ---------------------------------------------------------------------------
// Inputs q,k,v fp32 -> bf16 (fused)
// ---------------------------------------------------------------------------
__global__ __launch_bounds__(256) void cvt_x_kernel(
    const float* __restrict__ q, const float* __restrict__ k,
    const float* __restrict__ v, bf16_t* __restrict__ out) {
  const float* src = (blockIdx.y == 0) ? q : (blockIdx.y == 1) ? k : v;
  bf16_t* dst = out + (size_t)blockIdx.y * (M_ROWS * DM);
  int i = (blockIdx.x * 256 + threadIdx.x) * 8;
  float4 a = *(const float4*)(src + i);
  float4 b = *(const float4*)(src + i + 4);
  bf16x8 o;
  o[0] = (bf16_t)a.x; o[1] = (bf16_t)a.y; o[2] = (bf16_t)a.z; o[3] = (bf16_t)a.w;
  o[4] = (bf16_t)b.x; o[5] = (bf16_t)b.y; o[6] = (bf16_t)b.z; o[7] = (bf16_t)b.w;
  *(bf16x8*)(dst + i) = o;
}

// ---------------------------------------------------------------------------
// GEMM v4: Out = (X @ W^T + bias) * scale. Tile 64x128, BK=64, 3-stage LDS
// pipeline with raw-barrier async. XOR-swizzled LDS (16B chunks).
// omode 0: bf16 [bh][s][64]; 1: bf16 [bh][d][s]; 2: fp32 [m][512].
// ---------------------------------------------------------------------------
__device__ __forceinline__ void gemm_body64(
    const bf16_t* __restrict__ X, const bf16_t* __restrict__ Wm,
    const float* __restrict__ bias, void* __restrict__ Out,
    int omode, float scale) {
  __shared__ bf16_t Asm[3][64 * 64];
  __shared__ bf16_t Bsm[3][128 * 64];

  const int tid = threadIdx.x;
  const int w = tid >> 6;
  const int lane = tid & 63;
  const int quad = lane >> 4, l15 = lane & 15;
  const int l8 = lane >> 3;
  const int swcol = ((lane & 7) ^ l8) * 8;  // swizzled source col (elems)
  const int m0 = blockIdx.x * 64;
  const int n0 = blockIdx.y * 128;
  const int moff = (w & 1) * 32;
  const int noff = (w >> 1) * 64;

  f32x4 acc[2][4];
#pragma unroll
  for (int mb = 0; mb < 2; mb++)
#pragma unroll
    for (int nb = 0; nb < 4; nb++) { acc[mb][nb][0] = 0.f; acc[mb][nb][1] = 0.f; acc[mb][nb][2] = 0.f; acc[mb][nb][3] = 0.f; }

  // stage K-step ks into LDS buffer bufi (6 GLLs per thread: 4 B + 2 A)
  auto stage = [&](int ks, int bufi) {
    const int k0 = ks * 64;
#pragma unroll
    for (int j = 0; j < 4; j++) {
      const int row = j * 32 + w * 8 + l8;
      GLL(Wm + (size_t)(n0 + row) * DM + k0 + swcol, &Bsm[bufi][(j * 256 + w * 64) * 8]);
    }
#pragma unroll
    for (int j = 0; j < 2; j++) {
      const int row = j * 32 + w * 8 + l8;
      GLL(X + (size_t)(m0 + row) * DM + k0 + swcol, &Asm[bufi][(j * 256 + w * 64) * 8]);
    }
  };

  stage(0, 0);
  stage(1, 1);

  for (int ks = 0; ks < 8; ks++) {
    WAIT_BARRIER_V6();             // step-ks tile landed everywhere; buffer
                                   // (ks-1)%3 free for reuse
    const int tn = (ks + 2 < 8) ? ks + 2 : 7;   // dummy re-issue keeps counts uniform
    stage(tn, (ks + 2) % 3);
    const int p = ks % 3;

#pragma unroll
    for (int kd = 0; kd < 2; kd++) {
      const int fch = (((kd << 2) + quad) ^ (l15 & 7)) << 3;
      bf16x8 bfr[4];
#pragma unroll
      for (int nb = 0; nb < 4; nb++)
        bfr[nb] = *(const bf16x8*)&Bsm[p][(noff + nb * 16 + l15) * 64 + fch];
#pragma unroll
      for (int mb = 0; mb < 2; mb++) {
        bf16x8 a = *(const bf16x8*)&Asm[p][(moff + mb * 16 + l15) * 64 + fch];
#pragma unroll
        for (int nb = 0; nb < 4; nb++) acc[mb][nb] = MFMA16(a, bfr[nb], acc[mb][nb]);
      }
    }
  }

  // ---- epilogue ----
#pragma unroll
  for (int nb = 0; nb < 4; nb++) {
    const int n = n0 + noff + nb * 16 + l15;
    const float bn = bias[n];
    const int h = n >> 6, dd = n & 63;
#pragma unroll
    for (int mb = 0; mb < 2; mb++) {
      const int mbase = m0 + moff + mb * 16 + quad * 4;
      const int bb = mbase >> 12, s = mbase & 4095;
      if (omode == 0) {
#pragma unroll
        for (int r = 0; r < 4; r++) {
          const float val = (acc[mb][nb][r] + bn) * scale;
          ((bf16_t*)Out)[(size_t)((bb * NH + h) * SEQ + s + r) * HD + dd] = (bf16_t)val;
        }
      } else if (omode == 1) {
        bf16x4 pk;
#pragma unroll
        for (int r = 0; r < 4; r++) pk[r] = (bf16_t)(acc[mb][nb][r] + bn);
        *(bf16x4*)&((bf16_t*)Out)[(((size_t)(bb * NH + h) * HD + dd) << 12) + s] = pk;
      } else {
#pragma unroll
        for (int r = 0; r < 4; r++)
          ((float*)Out)[(size_t)(mbase + r) * DM + n] = acc[mb][nb][r] + bn;
      }
    }
  }
}

// Fused QKV projection (bf16 inputs). Grid (128,4,3).
__global__ __launch_bounds__(256, 2) void qkv_kernel(
    const bf16_t* __restrict__ Xall, const bf16_t* __restrict__ Wall,
    const float* __restrict__ bq, const float* __restrict__ bk,
    const float* __restrict__ bv, bf16_t* __restrict__ Qb,
    bf16_t* __restrict__ Kb, bf16_t* __restrict__ Vb, float qscale) {
  const int z = blockIdx.z;
  const bf16_t* X = Xall + (size_t)z * (M_ROWS * DM);
  const float* bias = (z == 0) ? bq : (z == 1) ? bk : bv;
  bf16_t* Out = (z == 0) ? Qb : (z == 1) ? Kb : Vb;
  gemm_body64(X, Wall + (size_t)z * DM * DM, bias, Out,
              (z == 2) ? 1 : 0, (z == 0) ? qscale : 1.0f);
}

// Output projection. Grid (128,4).
__global__ __launch_bounds__(256, 2) void oproj_kernel(
    const bf16_t* __restrict__ X, const bf16_t* __restrict__ Wm,
    const float* __restrict__ bias, float* __restrict__ Out) {
  gemm_body64(X, Wm, bias, Out, 2, 1.0f);
}

// ---------------------------------------------------------------------------
// Flash attention v7:
//  * 4-stage K/V LDS pipeline (prefetch distance 2 tiles, vmcnt(4) steady)
//  * cross-iteration overlap: QK^T(t+1) MFMAs issued before softmax(t) VALU
//    so the matrix pipe drains QK(t+1) while the wave issues exp2/pack/permlane
//    of tile t; S-registers ping-pong (sA/sB) via explicit 2-unrolled loop.
//  * in-register P redistribution (permlane32/16 swaps), no P LDS.
//  * XCD-aware block swizzle: 1-D grid 512, each XCD owns 64 consecutive
//    blocks = 2 bh -> K/V working set 2MB per XCD L2 (was 16MB thrash).
// 32 q/wave, 128 q/block. Grid (512).
// ---------------------------------------------------------------------------
__global__ __launch_bounds__(256, 2) void attn_kernel(
    const bf16_t* __restrict__ Qb, const bf16_t* __restrict__ Kb,
    const bf16_t* __restrict__ Vb, const float* __restrict__ rel_pos,
    bf16_t* __restrict__ attn_out) {
  __shared__ bf16_t Kt[4][64 * 64];    // swizzled [kk][d], 4-stage
  __shared__ bf16_t Vt[4][64 * 64];    // swizzled [d][kk], 4-stage

  const int tid = threadIdx.x;
  const int w = tid >> 6;
  const int lane = tid & 63;
  const int quad = lane >> 4, l15 = lane & 15;

  // XCD swizzle: 512 blocks, 8 XCDs -> 64 consecutive per XCD (bijective)
  const int lin = blockIdx.x;
  const int glob = (lin & 7) * 64 + (lin >> 3);
  const int bh = glob >> 5;        // 2 bh per XCD
  const int qb = glob & 31;
  const int b = bh >> 3, h = bh & 7;
  const int qlo = qb * 128 + w * 32;

  const float rb0 = rel_pos[h * 5 + 0] * LOG2E;
  const float rb1 = rel_pos[h * 5 + 1] * LOG2E;
  const float rb2 = rel_pos[h * 5 + 2] * LOG2E;
  const float rb3 = rel_pos[h * 5 + 3] * LOG2E;
  const float rb4 = rel_pos[h * 5 + 4] * LOG2E;

  // Q fragments (B-operand): two q-groups of 16
  bf16x8 qf[2][2];
#pragma unroll
  for (int mb = 0; mb < 2; mb++)
#pragma unroll
    for (int kd = 0; kd < 2; kd++)
      qf[mb][kd] = *(const bf16x8*)(Qb + (size_t)(bh * SEQ + qlo + mb * 16 + l15) * HD + kd * 32 + 8 * quad);

  f32x4 o[2][4];
#pragma unroll
  for (int mb = 0; mb < 2; mb++)
#pragma unroll
    for (int db = 0; db < 4; db++) { o[mb][db][0] = 0.f; o[mb][db][1] = 0.f; o[mb][db][2] = 0.f; o[mb][db][3] = 0.f; }
  f32x4 l4[2];
  l4[0][0] = 0.f; l4[0][1] = 0.f; l4[0][2] = 0.f; l4[0][3] = 0.f;
  l4[1][0] = 0.f; l4[1][1] = 0.f; l4[1][2] = 0.f; l4[1][3] = 0.f;

  bf16x8 ones;
#pragma unroll
  for (int i = 0; i < 8; i++) ones[i] = (bf16_t)1.0f;

  // --- staging addresses (swizzled): phys chunk = logical ^ (row&7)
  const int srow = (w << 4) + (lane >> 3);
  const int scol = (((lane & 7) ^ (lane >> 3)) << 3);
  const bf16_t* kg0 = Kb + ((size_t)(bh * SEQ + srow) << 6) + scol;
  const bf16_t* vg0 = Vb + (((size_t)(bh * HD + srow)) << 12) + scol;
  const int ldst = (w << 10);  // wave's LDS dest (elems)

  // --- fragment read bases (swizzled)
  const int sw = l15 & 7;
  const int kfo0 = (l15 << 6) + ((quad ^ sw) << 3);
  const int kfo1 = (l15 << 6) + (((quad + 4) ^ sw) << 3);

  auto stage = [&](int t, int bufi) {
    GLL(kg0 + ((size_t)t << 12), &Kt[bufi][ldst]);
    GLL(kg0 + ((size_t)t << 12) + (8 << 6), &Kt[bufi][ldst + 512]);
    GLL(vg0 + (t << 6), &Vt[bufi][ldst]);
    GLL(vg0 + (t << 6) + (8 << 12), &Vt[bufi][ldst + 512]);
  };

  // QK^T for tile tq into s (acc init folds bias const + fixed shift)
  auto qk_tile = [&](int tq, f32x4 (&s)[2][4]) {
    const int kk0 = tq * 64;
    float cini;
    if (kk0 >= qlo + 33)            cini = rb4 - SHIFT;
    else if (kk0 + 63 <= qlo - 2)   cini = rb0 - SHIFT;
    else                            cini = -SHIFT;
#pragma unroll
    for (int mb = 0; mb < 2; mb++)
#pragma unroll
      for (int kb = 0; kb < 4; kb++) { s[mb][kb][0] = cini; s[mb][kb][1] = cini; s[mb][kb][2] = cini; s[mb][kb][3] = cini; }
    const int pq = tq & 3;
    __builtin_amdgcn_s_setprio(1);
#pragma unroll
    for (int kb = 0; kb < 4; kb++) {
      bf16x8 kA0 = *(const bf16x8*)&Kt[pq][kfo0 + (kb << 10)];
      bf16x8 kA1 = *(const bf16x8*)&Kt[pq][kfo1 + (kb << 10)];
      s[0][kb] = MFMA16(kA0, qf[0][0], s[0][kb]);
      s[0][kb] = MFMA16(kA1, qf[0][1], s[0][kb]);
      s[1][kb] = MFMA16(kA0, qf[1][0], s[1][kb]);
      s[1][kb] = MFMA16(kA1, qf[1][1], s[1][kb]);
    }
    __builtin_amdgcn_s_setprio(0);
  };

  // softmax(t) on s + l accumulation + PV(t)
  auto sm_pv = [&](int t, f32x4 (&s)[2][4]) {
    const int kk0 = t * 64;
    const bool nearband = !(kk0 >= qlo + 33) && !(kk0 + 63 <= qlo - 2);
    if (nearband) {
#pragma unroll
      for (int mb = 0; mb < 2; mb++) {
        const int qg = qlo + mb * 16 + l15;
#pragma unroll
        for (int kb = 0; kb < 4; kb++)
#pragma unroll
          for (int r = 0; r < 4; r++) {
            int dl = kk0 + kb * 16 + quad * 4 + r - qg;
            float bias = dl <= -2 ? rb0
                       : (dl >= 2 ? rb4
                       : (dl == -1 ? rb1 : (dl == 0 ? rb2 : rb3)));
            s[mb][kb][r] += bias;
          }
      }
    }

    // p = exp2(s) -> bf16 pack -> in-register redistribution
    bf16x8 pf[2][2];
#pragma unroll
    for (int mb = 0; mb < 2; mb++) {
      unsigned int u[4][2];
#pragma unroll
      for (int kb = 0; kb < 4; kb++) {
        bf16x2 p0, p1;
        p0[0] = (bf16_t)__builtin_amdgcn_exp2f(s[mb][kb][0]);
        p0[1] = (bf16_t)__builtin_amdgcn_exp2f(s[mb][kb][1]);
        p1[0] = (bf16_t)__builtin_amdgcn_exp2f(s[mb][kb][2]);
        p1[1] = (bf16_t)__builtin_amdgcn_exp2f(s[mb][kb][3]);
        u[kb][0] = __builtin_bit_cast(unsigned int, p0);
        u[kb][1] = __builtin_bit_cast(unsigned int, p1);
      }
#pragma unroll
      for (int kc = 0; kc < 2; kc++) {
        unsigned int a0 = u[2 * kc][0], b0 = u[2 * kc + 1][0];
        unsigned int a1 = u[2 * kc][1], b1 = u[2 * kc + 1][1];
        asm("v_permlane32_swap_b32 %0, %1" : "+v"(a0), "+v"(b0));
        asm("v_permlane32_swap_b32 %0, %1" : "+v"(a1), "+v"(b1));
        asm("v_permlane16_swap_b32 %0, %1" : "+v"(a0), "+v"(b0));
        asm("v_permlane16_swap_b32 %0, %1" : "+v"(a1), "+v"(b1));
        u32x4 pk; pk[0] = a0; pk[1] = a1; pk[2] = b0; pk[3] = b1;
        pf[mb][kc] = __builtin_bit_cast(bf16x8, pk);
      }
    }

    const int p = t & 3;
    __builtin_amdgcn_s_setprio(1);
    l4[0] = MFMA16(ones, pf[0][0], l4[0]);
    l4[0] = MFMA16(ones, pf[0][1], l4[0]);
    l4[1] = MFMA16(ones, pf[1][0], l4[1]);
    l4[1] = MFMA16(ones, pf[1][1], l4[1]);
#pragma unroll
    for (int db = 0; db < 4; db++) {
      bf16x8 vA0 = *(const bf16x8*)&Vt[p][kfo0 + (db << 10)];
      bf16x8 vA1 = *(const bf16x8*)&Vt[p][kfo1 + (db << 10)];
      o[0][db] = MFMA16(vA0, pf[0][0], o[0][db]);
      o[0][db] = MFMA16(vA1, pf[0][1], o[0][db]);
      o[1][db] = MFMA16(vA0, pf[1][0], o[1][db]);
      o[1][db] = MFMA16(vA1, pf[1][1], o[1][db]);
    }
    __builtin_amdgcn_s_setprio(0);
  };

  // prologue: 3 tiles in flight, wait tile 0, compute QK(0)
  stage(0, 0);
  stage(1, 1);
  stage(2, 2);
  WAIT_BARRIER_V8();               // tile 0 landed (tiles 1,2 in flight)

  f32x4 sA[2][4], sB[2][4];
  qk_tile(0, sA);

  for (int t2 = 0; t2 < 32; t2++) {
    {
      const int t = 2 * t2;        // even: sA holds S(t), QK(t+1) -> sB
      WAIT_BARRIER_V4();           // tile t+1 landed; all waves done iter t-1
      const int tg = (t + 3 < 64) ? t + 3 : 63;
      stage(tg, (t + 3) & 3);      // overwrites buf (t-1)&3
      qk_tile(t + 1, sB);          // MFMA pipe fills while softmax(t) issues
      sm_pv(t, sA);
    }
    {
      const int t = 2 * t2 + 1;    // odd: sB holds S(t), QK(t+1) -> sA
      WAIT_BARRIER_V4();
      const int tg = (t + 3 < 64) ? t + 3 : 63;
      stage(tg, (t + 3) & 3);
      if (t < 63) qk_tile(t + 1, sA);
      sm_pv(t, sB);
    }
  }

  // ---- epilogue: O^T / l ----
#pragma unroll
  for (int mb = 0; mb < 2; mb++) {
    const float inv = 1.0f / l4[mb][0];
    const int qg = qlo + mb * 16 + l15;
#pragma unroll
    for (int db = 0; db < 4; db++) {
      bf16x4 pk;
#pragma unroll
      for (int r = 0; r < 4; r++) pk[r] = (bf16_t)(o[mb][db][r] * inv);
      *(bf16x4*)(attn_out + (size_t)(b * SEQ + qg) * DM + h * HD + db * 16 + quad * 4) = pk;
    }
  }
}

// ---------------------------------------------------------------------------
extern "C" void kernel_launch(void* const* d_in, const int* in_sizes, int n_in,
                              void* d_out, int out_size, void* d_ws, size_t ws_size,
                              hipStream_t stream) {
  const float* q   = (const float*)d_in[0];
  const float* k   = (const float*)d_in[1];
  const float* v   = (const float*)d_in[2];
  const float* Wq  = (const float*)d_in[3];
  const float* bq  = (const float*)d_in[4];
  const float* Wk  = (const float*)d_in[5];
  const float* bk  = (const float*)d_in[6];
  const float* Wv  = (const float*)d_in[7];
  const float* bv  = (const float*)d_in[8];
  const float* Wo  = (const float*)d_in[9];
  const float* bo  = (const float*)d_in[10];
  const float* rel = (const float*)d_in[11];

  char* ws = (char*)d_ws;
  bf16_t* Wbf  = (bf16_t*)ws;                               // 2MB (4 matrices)
  bf16_t* Xb   = (bf16_t*)(ws + (size_t)(2  << 20));        // 24MB bf16 q,k,v
  bf16_t* Qbuf = (bf16_t*)(ws + (size_t)(26 << 20));        // 8MB [bh][s][64]
  bf16_t* Kbuf = (bf16_t*)(ws + (size_t)(34 << 20));        // 8MB [bh][s][64]
  bf16_t* Vbuf = (bf16_t*)(ws + (size_t)(42 << 20));        // 8MB [bh][d][s]
  bf16_t* Abuf = (bf16_t*)(ws + (size_t)(2  << 20));        // alias Xb (dead after qkv)

  cvt_w_kernel<<<dim3(256, 4), 256, 0, stream>>>(Wq, Wk, Wv, Wo, Wbf);
  cvt_x_kernel<<<dim3(2048, 3), 256, 0, stream>>>(q, k, v, Xb);

  const float qscale = LOG2E / 8.0f;  // fold 1/sqrt(64) + exp2 domain
  qkv_kernel<<<dim3(128, 4, 3), 256, 0, stream>>>(
      Xb, Wbf, bq, bk, bv, Qbuf, Kbuf, Vbuf, qscale);

  attn_kernel<<<512, 256, 0, stream>>>(Qbuf, Kbuf, Vbuf, rel, Abuf);

  oproj_kernel<<<dim3(128, 4), 256, 0, stream>>>(Abuf, Wbf + 3 * DM * DM, bo, (float*)d_out);
}

// Round 4
// 230.760 us; speedup vs baseline: 1.0371x; 1.0084x over previous
//
#include <hip/hip_runtime.h>

typedef __bf16 bf16_t;
typedef __bf16 bf16x2 __attribute__((ext_vector_type(2)));
typedef __bf16 bf16x4 __attribute__((ext_vector_type(4)));
typedef __bf16 bf16x8 __attribute__((ext_vector_type(8)));
typedef float f32x4 __attribute__((ext_vector_type(4)));
typedef unsigned int u32x4 __attribute__((ext_vector_type(4)));

#define MFMA16(a, b, c) __builtin_amdgcn_mfma_f32_16x16x32_bf16(a, b, c, 0, 0, 0)
#define LOG2E 1.4426950408889634f
#define SHIFT 16.0f

// async global -> LDS, 16B per lane (LDS dest = wave-uniform base + lane*16)
#define GLL(g, l)                                                      \
  __builtin_amdgcn_global_load_lds(                                    \
      (const __attribute__((address_space(1))) void*)(g),              \
      (__attribute__((address_space(3))) void*)(l), 16, 0, 0)

// raw barrier: wait only the OLDEST in-flight GLLs (newest stay in flight),
// then s_barrier WITHOUT the compiler's vmcnt(0) drain.
#define WAIT_BARRIER_V4() asm volatile("s_waitcnt vmcnt(4)\n\ts_barrier" ::: "memory")
#define WAIT_BARRIER_V6() asm volatile("s_waitcnt vmcnt(6)\n\ts_barrier" ::: "memory")
#define WAIT_BARRIER_V8() asm volatile("s_waitcnt vmcnt(8)\n\ts_barrier" ::: "memory")

static constexpr int NB = 2;
static constexpr int SEQ = 4096;
static constexpr int DM = 512;
static constexpr int NH = 8;
static constexpr int HD = 64;
static constexpr int M_ROWS = NB * SEQ;  // 8192

// ---------------------------------------------------------------------------
// Weights fp32 -> bf16
// ---------------------------------------------------------------------------
__global__ __launch_bounds__(256) void cvt_w_kernel(
    const float* __restrict__ w0, const float* __restrict__ w1,
    const float* __restrict__ w2, const float* __restrict__ w3,
    bf16_t* __restrict__ out) {
  const float* src = (blockIdx.y == 0) ? w0 : (blockIdx.y == 1) ? w1
                   : (blockIdx.y == 2) ? w2 : w3;
  int i = (blockIdx.x * 256 + threadIdx.x) * 4;
  float4 v = *(const float4*)(src + i);
  bf16_t* o = out + blockIdx.y * (DM * DM) + i;
  o[0] = (bf16_t)v.x; o[1] = (bf16_t)v.y; o[2] = (bf16_t)v.z; o[3] = (bf16_t)v.w;
}

// ---------------------------------------------------------------------------
// Inputs q,k,v fp32 -> bf16 (fused)
// ---------------------------------------------------------------------------
__global__ __launch_bounds__(256) void cvt_x_kernel(
    const float* __restrict__ q, const float* __restrict__ k,
    const float* __restrict__ v, bf16_t* __restrict__ out) {
  const float* src = (blockIdx.y == 0) ? q : (blockIdx.y == 1) ? k : v;
  bf16_t* dst = out + (size_t)blockIdx.y * (M_ROWS * DM);
  int i = (blockIdx.x * 256 + threadIdx.x) * 8;
  float4 a = *(const float4*)(src + i);
  float4 b = *(const float4*)(src + i + 4);
  bf16x8 o;
  o[0] = (bf16_t)a.x; o[1] = (bf16_t)a.y; o[2] = (bf16_t)a.z; o[3] = (bf16_t)a.w;
  o[4] = (bf16_t)b.x; o[5] = (bf16_t)b.y; o[6] = (bf16_t)b.z; o[7] = (bf16_t)b.w;
  *(bf16x8*)(dst + i) = o;
}

// ---------------------------------------------------------------------------
// GEMM v4: Out = (X @ W^T + bias) * scale. Tile 64x128, BK=64, 3-stage LDS
// pipeline with raw-barrier async. XOR-swizzled LDS (16B chunks).
// omode 0: bf16 [bh][s][64]; 1: bf16 [bh][d][s]; 2: fp32 [m][512].
// ---------------------------------------------------------------------------
__device__ __forceinline__ void gemm_body64(
    const bf16_t* __restrict__ X, const bf16_t* __restrict__ Wm,
    const float* __restrict__ bias, void* __restrict__ Out,
    int omode, float scale) {
  __shared__ bf16_t Asm[3][64 * 64];
  __shared__ bf16_t Bsm[3][128 * 64];

  const int tid = threadIdx.x;
  const int w = tid >> 6;
  const int lane = tid & 63;
  const int quad = lane >> 4, l15 = lane & 15;
  const int l8 = lane >> 3;
  const int swcol = ((lane & 7) ^ l8) * 8;  // swizzled source col (elems)
  const int m0 = blockIdx.x * 64;
  const int n0 = blockIdx.y * 128;
  const int moff = (w & 1) * 32;
  const int noff = (w >> 1) * 64;

  f32x4 acc[2][4];
#pragma unroll
  for (int mb = 0; mb < 2; mb++)
#pragma unroll
    for (int nb = 0; nb < 4; nb++) { acc[mb][nb][0] = 0.f; acc[mb][nb][1] = 0.f; acc[mb][nb][2] = 0.f; acc[mb][nb][3] = 0.f; }

  // stage K-step ks into LDS buffer bufi (6 GLLs per thread: 4 B + 2 A)
  auto stage = [&](int ks, int bufi) {
    const int k0 = ks * 64;
#pragma unroll
    for (int j = 0; j < 4; j++) {
      const int row = j * 32 + w * 8 + l8;
      GLL(Wm + (size_t)(n0 + row) * DM + k0 + swcol, &Bsm[bufi][(j * 256 + w * 64) * 8]);
    }
#pragma unroll
    for (int j = 0; j < 2; j++) {
      const int row = j * 32 + w * 8 + l8;
      GLL(X + (size_t)(m0 + row) * DM + k0 + swcol, &Asm[bufi][(j * 256 + w * 64) * 8]);
    }
  };

  stage(0, 0);
  stage(1, 1);

  for (int ks = 0; ks < 8; ks++) {
    WAIT_BARRIER_V6();             // step-ks tile landed everywhere; buffer
                                   // (ks-1)%3 free for reuse
    const int tn = (ks + 2 < 8) ? ks + 2 : 7;   // dummy re-issue keeps counts uniform
    stage(tn, (ks + 2) % 3);
    const int p = ks % 3;

#pragma unroll
    for (int kd = 0; kd < 2; kd++) {
      const int fch = (((kd << 2) + quad) ^ (l15 & 7)) << 3;
      bf16x8 bfr[4];
#pragma unroll
      for (int nb = 0; nb < 4; nb++)
        bfr[nb] = *(const bf16x8*)&Bsm[p][(noff + nb * 16 + l15) * 64 + fch];
#pragma unroll
      for (int mb = 0; mb < 2; mb++) {
        bf16x8 a = *(const bf16x8*)&Asm[p][(moff + mb * 16 + l15) * 64 + fch];
#pragma unroll
        for (int nb = 0; nb < 4; nb++) acc[mb][nb] = MFMA16(a, bfr[nb], acc[mb][nb]);
      }
    }
  }

  // ---- epilogue ----
#pragma unroll
  for (int nb = 0; nb < 4; nb++) {
    const int n = n0 + noff + nb * 16 + l15;
    const float bn = bias[n];
    const int h = n >> 6, dd = n & 63;
#pragma unroll
    for (int mb = 0; mb < 2; mb++) {
      const int mbase = m0 + moff + mb * 16 + quad * 4;
      const int bb = mbase >> 12, s = mbase & 4095;
      if (omode == 0) {
#pragma unroll
        for (int r = 0; r < 4; r++) {
          const float val = (acc[mb][nb][r] + bn) * scale;
          ((bf16_t*)Out)[(size_t)((bb * NH + h) * SEQ + s + r) * HD + dd] = (bf16_t)val;
        }
      } else if (omode == 1) {
        bf16x4 pk;
#pragma unroll
        for (int r = 0; r < 4; r++) pk[r] = (bf16_t)(acc[mb][nb][r] + bn);
        *(bf16x4*)&((bf16_t*)Out)[(((size_t)(bb * NH + h) * HD + dd) << 12) + s] = pk;
      } else {
#pragma unroll
        for (int r = 0; r < 4; r++)
          ((float*)Out)[(size_t)(mbase + r) * DM + n] = acc[mb][nb][r] + bn;
      }
    }
  }
}

// Fused QKV projection (bf16 inputs). Grid (128,4,3).
__global__ __launch_bounds__(256, 2) void qkv_kernel(
    const bf16_t* __restrict__ Xall, const bf16_t* __restrict__ Wall,
    const float* __restrict__ bq, const float* __restrict__ bk,
    const float* __restrict__ bv, bf16_t* __restrict__ Qb,
    bf16_t* __restrict__ Kb, bf16_t* __restrict__ Vb, float qscale) {
  const int z = blockIdx.z;
  const bf16_t* X = Xall + (size_t)z * (M_ROWS * DM);
  const float* bias = (z == 0) ? bq : (z == 1) ? bk : bv;
  bf16_t* Out = (z == 0) ? Qb : (z == 1) ? Kb : Vb;
  gemm_body64(X, Wall + (size_t)z * DM * DM, bias, Out,
              (z == 2) ? 1 : 0, (z == 0) ? qscale : 1.0f);
}

// Output projection. Grid (128,4).
__global__ __launch_bounds__(256, 2) void oproj_kernel(
    const bf16_t* __restrict__ X, const bf16_t* __restrict__ Wm,
    const float* __restrict__ bias, float* __restrict__ Out) {
  gemm_body64(X, Wm, bias, Out, 2, 1.0f);
}

// ---------------------------------------------------------------------------
// Flash attention v8: 2x2 wave-role split.
// Waves (wq,wk) = (w>>1, w&1): wq picks 64-q half of the block's 128 q,
// wk picks a 32-kk half of each 64-kk tile. Per wave-tile: 4 K-reads -> 16
// QK MFMAs, 4 V-reads -> 16 PV MFMAs (each LDS fragment feeds 4 MFMAs, was
// 2) -- halves per-CU LDS read traffic, which the post-barrier burst made
// the binding resource. O,l are k-partial per wave; one cross-wave LDS
// reduction at kernel end (reusing Kt/Vt space).
// Retained: 4-stage K/V pipeline (vmcnt(4) steady), QK(t+1)||softmax(t)
// ping-pong, in-register P redistribution, XCD-aware swizzle.
// Grid (512).
// ---------------------------------------------------------------------------
__global__ __launch_bounds__(256, 2) void attn_kernel(
    const bf16_t* __restrict__ Qb, const bf16_t* __restrict__ Kb,
    const bf16_t* __restrict__ Vb, const float* __restrict__ rel_pos,
    bf16_t* __restrict__ attn_out) {
  __shared__ bf16_t Kt[4][64 * 64];    // swizzled [kk][d], 4-stage
  __shared__ bf16_t Vt[4][64 * 64];    // swizzled [d][kk], 4-stage

  const int tid = threadIdx.x;
  const int w = tid >> 6;
  const int lane = tid & 63;
  const int quad = lane >> 4, l15 = lane & 15;
  const int wq = w >> 1, wk = w & 1;

  // XCD swizzle: 512 blocks, 8 XCDs -> 64 consecutive per XCD (bijective)
  const int lin = blockIdx.x;
  const int glob = (lin & 7) * 64 + (lin >> 3);
  const int bh = glob >> 5;        // 2 bh per XCD
  const int qb = glob & 31;
  const int b = bh >> 3, h = bh & 7;
  const int qlo = qb * 128 + wq * 64;  // wave's 64-q base

  const float rb0 = rel_pos[h * 5 + 0] * LOG2E;
  const float rb1 = rel_pos[h * 5 + 1] * LOG2E;
  const float rb2 = rel_pos[h * 5 + 2] * LOG2E;
  const float rb3 = rel_pos[h * 5 + 3] * LOG2E;
  const float rb4 = rel_pos[h * 5 + 4] * LOG2E;

  // Q fragments (B-operand): four q-groups of 16
  bf16x8 qf[4][2];
#pragma unroll
  for (int mb = 0; mb < 4; mb++)
#pragma unroll
    for (int kd = 0; kd < 2; kd++)
      qf[mb][kd] = *(const bf16x8*)(Qb + (size_t)(bh * SEQ + qlo + mb * 16 + l15) * HD + kd * 32 + 8 * quad);

  f32x4 o[4][4];
#pragma unroll
  for (int mb = 0; mb < 4; mb++)
#pragma unroll
    for (int db = 0; db < 4; db++) { o[mb][db][0] = 0.f; o[mb][db][1] = 0.f; o[mb][db][2] = 0.f; o[mb][db][3] = 0.f; }
  f32x4 l4[4];
#pragma unroll
  for (int mb = 0; mb < 4; mb++) { l4[mb][0] = 0.f; l4[mb][1] = 0.f; l4[mb][2] = 0.f; l4[mb][3] = 0.f; }

  bf16x8 ones;
#pragma unroll
  for (int i = 0; i < 8; i++) ones[i] = (bf16_t)1.0f;

  // --- staging addresses (swizzled): phys chunk = logical ^ (row&7)
  const int srow = (w << 4) + (lane >> 3);
  const int scol = (((lane & 7) ^ (lane >> 3)) << 3);
  const bf16_t* kg0 = Kb + ((size_t)(bh * SEQ + srow) << 6) + scol;
  const bf16_t* vg0 = Vb + (((size_t)(bh * HD + srow)) << 12) + scol;
  const int ldst = (w << 10);  // wave's LDS dest (elems)

  // --- fragment read bases (swizzled)
  const int sw = l15 & 7;
  const int kfo0 = (l15 << 6) + ((quad ^ sw) << 3);             // d-half 0
  const int kfo1 = (l15 << 6) + (((quad + 4) ^ sw) << 3);       // d-half 1
  // V fragment: logical kk-chunk = wk*4 + quad
  const int vfo = (l15 << 6) + ((((wk << 2) + quad) ^ sw) << 3);
  const int wk2 = wk << 1;     // row-block base for K reads (wk half)

  auto stage = [&](int t, int bufi) {
    GLL(kg0 + ((size_t)t << 12), &Kt[bufi][ldst]);
    GLL(kg0 + ((size_t)t << 12) + (8 << 6), &Kt[bufi][ldst + 512]);
    GLL(vg0 + (t << 6), &Vt[bufi][ldst]);
    GLL(vg0 + (t << 6) + (8 << 12), &Vt[bufi][ldst + 512]);
  };

  // QK^T for wave's 32-kk slice of tile tq (acc init folds bias const+shift)
  auto qk_tile = [&](int tq, f32x4 (&s)[4][2]) {
    const int klo = tq * 64 + wk * 32;
    float cini;
    if (klo >= qlo + 65)        cini = rb4 - SHIFT;
    else if (klo <= qlo - 33)   cini = rb0 - SHIFT;
    else                        cini = -SHIFT;
#pragma unroll
    for (int mb = 0; mb < 4; mb++)
#pragma unroll
      for (int kb = 0; kb < 2; kb++) { s[mb][kb][0] = cini; s[mb][kb][1] = cini; s[mb][kb][2] = cini; s[mb][kb][3] = cini; }
    const int pq = tq & 3;
    __builtin_amdgcn_s_setprio(1);
#pragma unroll
    for (int kb = 0; kb < 2; kb++) {
      bf16x8 kA0 = *(const bf16x8*)&Kt[pq][kfo0 + ((wk2 + kb) << 10)];
      bf16x8 kA1 = *(const bf16x8*)&Kt[pq][kfo1 + ((wk2 + kb) << 10)];
      s[0][kb] = MFMA16(kA0, qf[0][0], s[0][kb]);
      s[0][kb] = MFMA16(kA1, qf[0][1], s[0][kb]);
      s[1][kb] = MFMA16(kA0, qf[1][0], s[1][kb]);
      s[1][kb] = MFMA16(kA1, qf[1][1], s[1][kb]);
      s[2][kb] = MFMA16(kA0, qf[2][0], s[2][kb]);
      s[2][kb] = MFMA16(kA1, qf[2][1], s[2][kb]);
      s[3][kb] = MFMA16(kA0, qf[3][0], s[3][kb]);
      s[3][kb] = MFMA16(kA1, qf[3][1], s[3][kb]);
    }
    __builtin_amdgcn_s_setprio(0);
  };

  // softmax on wave's slice + l accumulation + partial PV
  auto sm_pv = [&](int t, f32x4 (&s)[4][2]) {
    const int klo = t * 64 + wk * 32;
    const bool nearband = !(klo >= qlo + 65) && !(klo <= qlo - 33);
    if (nearband) {
#pragma unroll
      for (int mb = 0; mb < 4; mb++) {
        const int qg = qlo + mb * 16 + l15;
#pragma unroll
        for (int kb = 0; kb < 2; kb++)
#pragma unroll
          for (int r = 0; r < 4; r++) {
            int dl = klo + kb * 16 + quad * 4 + r - qg;
            float bias = dl <= -2 ? rb0
                       : (dl >= 2 ? rb4
                       : (dl == -1 ? rb1 : (dl == 0 ? rb2 : rb3)));
            s[mb][kb][r] += bias;
          }
      }
    }

    // p = exp2(s) -> bf16 pack -> in-register redistribution (one frag/mb)
    bf16x8 pf[4];
#pragma unroll
    for (int mb = 0; mb < 4; mb++) {
      unsigned int u[2][2];
#pragma unroll
      for (int kb = 0; kb < 2; kb++) {
        bf16x2 p0, p1;
        p0[0] = (bf16_t)__builtin_amdgcn_exp2f(s[mb][kb][0]);
        p0[1] = (bf16_t)__builtin_amdgcn_exp2f(s[mb][kb][1]);
        p1[0] = (bf16_t)__builtin_amdgcn_exp2f(s[mb][kb][2]);
        p1[1] = (bf16_t)__builtin_amdgcn_exp2f(s[mb][kb][3]);
        u[kb][0] = __builtin_bit_cast(unsigned int, p0);
        u[kb][1] = __builtin_bit_cast(unsigned int, p1);
      }
      unsigned int a0 = u[0][0], b0 = u[1][0];
      unsigned int a1 = u[0][1], b1 = u[1][1];
      asm("v_permlane32_swap_b32 %0, %1" : "+v"(a0), "+v"(b0));
      asm("v_permlane32_swap_b32 %0, %1" : "+v"(a1), "+v"(b1));
      asm("v_permlane16_swap_b32 %0, %1" : "+v"(a0), "+v"(b0));
      asm("v_permlane16_swap_b32 %0, %1" : "+v"(a1), "+v"(b1));
      u32x4 pk; pk[0] = a0; pk[1] = a1; pk[2] = b0; pk[3] = b1;
      pf[mb] = __builtin_bit_cast(bf16x8, pk);
    }

    const int p = t & 3;
    __builtin_amdgcn_s_setprio(1);
    l4[0] = MFMA16(ones, pf[0], l4[0]);
    l4[1] = MFMA16(ones, pf[1], l4[1]);
    l4[2] = MFMA16(ones, pf[2], l4[2]);
    l4[3] = MFMA16(ones, pf[3], l4[3]);
#pragma unroll
    for (int db = 0; db < 4; db++) {
      bf16x8 vA = *(const bf16x8*)&Vt[p][vfo + (db << 10)];
      o[0][db] = MFMA16(vA, pf[0], o[0][db]);
      o[1][db] = MFMA16(vA, pf[1], o[1][db]);
      o[2][db] = MFMA16(vA, pf[2], o[2][db]);
      o[3][db] = MFMA16(vA, pf[3], o[3][db]);
    }
    __builtin_amdgcn_s_setprio(0);
  };

  // prologue: 3 tiles in flight, wait tile 0, compute QK(0)
  stage(0, 0);
  stage(1, 1);
  stage(2, 2);
  WAIT_BARRIER_V8();               // tile 0 landed (tiles 1,2 in flight)

  f32x4 sA[4][2], sB[4][2];
  qk_tile(0, sA);

  for (int t2 = 0; t2 < 32; t2++) {
    {
      const int t = 2 * t2;        // even: sA holds S(t), QK(t+1) -> sB
      WAIT_BARRIER_V4();           // tile t+1 landed; all waves done iter t-1
      const int tg = (t + 3 < 64) ? t + 3 : 63;
      stage(tg, (t + 3) & 3);      // overwrites buf (t-1)&3
      qk_tile(t + 1, sB);          // MFMA pipe fills while softmax(t) issues
      sm_pv(t, sA);
    }
    {
      const int t = 2 * t2 + 1;    // odd: sB holds S(t), QK(t+1) -> sA
      WAIT_BARRIER_V4();
      const int tg = (t + 3 < 64) ? t + 3 : 63;
      stage(tg, (t + 3) & 3);
      if (t < 63) qk_tile(t + 1, sA);
      sm_pv(t, sB);
    }
  }

  // ---- cross-wave (wk) reduction of partial O,l via LDS, then epilogue ----
  asm volatile("s_waitcnt vmcnt(0)" ::: "memory");  // dummy stages landed
  __syncthreads();
  float* Ored = (float*)&Kt[0][0];   // 2 x 16KB (per wq)
  float* lred = (float*)&Vt[0][0];   // 2 x 256B
  if (wk) {
#pragma unroll
    for (int mb = 0; mb < 4; mb++) {
      lred[(wq << 6) + (mb << 4) + l15] = l4[mb][0];
#pragma unroll
      for (int db = 0; db < 4; db++) {
        const int ch = ((db << 2) | quad) ^ sw;
        *(f32x4*)&Ored[(wq << 12) + ((mb * 16 + l15) << 6) + (ch << 2)] = o[mb][db];
      }
    }
  }
  __syncthreads();
  if (!wk) {
#pragma unroll
    for (int mb = 0; mb < 4; mb++) {
      float lsum = l4[mb][0] + lred[(wq << 6) + (mb << 4) + l15];
      const float inv = 1.0f / lsum;
      const int qg = qlo + mb * 16 + l15;
#pragma unroll
      for (int db = 0; db < 4; db++) {
        const int ch = ((db << 2) | quad) ^ sw;
        const f32x4 part = *(const f32x4*)&Ored[(wq << 12) + ((mb * 16 + l15) << 6) + (ch << 2)];
        bf16x4 pk;
#pragma unroll
        for (int r = 0; r < 4; r++) pk[r] = (bf16_t)((o[mb][db][r] + part[r]) * inv);
        *(bf16x4*)(attn_out + (size_t)(b * SEQ + qg) * DM + h * HD + db * 16 + quad * 4) = pk;
      }
    }
  }
}

// ---------------------------------------------------------------------------
extern "C" void kernel_launch(void* const* d_in, const int* in_sizes, int n_in,
                              void* d_out, int out_size, void* d_ws, size_t ws_size,
                              hipStream_t stream) {
  const float* q   = (const float*)d_in[0];
  const float* k   = (const float*)d_in[1];
  const float* v   = (const float*)d_in[2];
  const float* Wq  = (const float*)d_in[3];
  const float* bq  = (const float*)d_in[4];
  const float* Wk  = (const float*)d_in[5];
  const float* bk  = (const float*)d_in[6];
  const float* Wv  = (const float*)d_in[7];
  const float* bv  = (const float*)d_in[8];
  const float* Wo  = (const float*)d_in[9];
  const float* bo  = (const float*)d_in[10];
  const float* rel = (const float*)d_in[11];

  char* ws = (char*)d_ws;
  bf16_t* Wbf  = (bf16_t*)ws;                               // 2MB (4 matrices)
  bf16_t* Xb   = (bf16_t*)(ws + (size_t)(2  << 20));        // 24MB bf16 q,k,v
  bf16_t* Qbuf = (bf16_t*)(ws + (size_t)(26 << 20));        // 8MB [bh][s][64]
  bf16_t* Kbuf = (bf16_t*)(ws + (size_t)(34 << 20));        // 8MB [bh][s][64]
  bf16_t* Vbuf = (bf16_t*)(ws + (size_t)(42 << 20));        // 8MB [bh][d][s]
  bf16_t* Abuf = (bf16_t*)(ws + (size_t)(2  << 20));        // alias Xb (dead after qkv)

  cvt_w_kernel<<<dim3(256, 4), 256, 0, stream>>>(Wq, Wk, Wv, Wo, Wbf);
  cvt_x_kernel<<<dim3(2048, 3), 256, 0, stream>>>(q, k, v, Xb);

  const float qscale = LOG2E / 8.0f;  // fold 1/sqrt(64) + exp2 domain
  qkv_kernel<<<dim3(128, 4, 3), 256, 0, stream>>>(
      Xb, Wbf, bq, bk, bv, Qbuf, Kbuf, Vbuf, qscale);

  attn_kernel<<<512, 256, 0, stream>>>(Qbuf, Kbuf, Vbuf, rel, Abuf);

  oproj_kernel<<<dim3(128, 4), 256, 0, stream>>>(Abuf, Wbf + 3 * DM * DM, bo, (float*)d_out);
}

// Round 5
// 227.173 us; speedup vs baseline: 1.0535x; 1.0158x over previous
//
#include <hip/hip_runtime.h>

typedef __bf16 bf16_t;
typedef __bf16 bf16x2 __attribute__((ext_vector_type(2)));
typedef __bf16 bf16x4 __attribute__((ext_vector_type(4)));
typedef __bf16 bf16x8 __attribute__((ext_vector_type(8)));
typedef float f32x4 __attribute__((ext_vector_type(4)));
typedef unsigned int u32x4 __attribute__((ext_vector_type(4)));

#define MFMA16(a, b, c) __builtin_amdgcn_mfma_f32_16x16x32_bf16(a, b, c, 0, 0, 0)
#define LOG2E 1.4426950408889634f
#define SHIFT 16.0f

// async global -> LDS, 16B per lane (LDS dest = wave-uniform base + lane*16)
#define GLL(g, l)                                                      \
  __builtin_amdgcn_global_load_lds(                                    \
      (const __attribute__((address_space(1))) void*)(g),              \
      (__attribute__((address_space(3))) void*)(l), 16, 0, 0)

// raw barrier variants: wait N oldest in-flight GLLs, then s_barrier without
// the compiler's full drain.
#define WAIT_BARRIER_V0() asm volatile("s_waitcnt vmcnt(0)\n\ts_barrier" ::: "memory")
#define WAIT_BARRIER_V6() asm volatile("s_waitcnt vmcnt(6)\n\ts_barrier" ::: "memory")

static constexpr int NB = 2;
static constexpr int SEQ = 4096;
static constexpr int DM = 512;
static constexpr int NH = 8;
static constexpr int HD = 64;
static constexpr int M_ROWS = NB * SEQ;  // 8192

// ---------------------------------------------------------------------------
// Weights fp32 -> bf16
// ---------------------------------------------------------------------------
__global__ __launch_bounds__(256) void cvt_w_kernel(
    const float* __restrict__ w0, const float* __restrict__ w1,
    const float* __restrict__ w2, const float* __restrict__ w3,
    bf16_t* __restrict__ out) {
  const float* src = (blockIdx.y == 0) ? w0 : (blockIdx.y == 1) ? w1
                   : (blockIdx.y == 2) ? w2 : w3;
  int i = (blockIdx.x * 256 + threadIdx.x) * 4;
  float4 v = *(const float4*)(src + i);
  bf16_t* o = out + blockIdx.y * (DM * DM) + i;
  o[0] = (bf16_t)v.x; o[1] = (bf16_t)v.y; o[2] = (bf16_t)v.z; o[3] = (bf16_t)v.w;
}

// ---------------------------------------------------------------------------
// Inputs q,k,v fp32 -> bf16 (fused)
// ---------------------------------------------------------------------------
__global__ __launch_bounds__(256) void cvt_x_kernel(
    const float* __restrict__ q, const float* __restrict__ k,
    const float* __restrict__ v, bf16_t* __restrict__ out) {
  const float* src = (blockIdx.y == 0) ? q : (blockIdx.y == 1) ? k : v;
  bf16_t* dst = out + (size_t)blockIdx.y * (M_ROWS * DM);
  int i = (blockIdx.x * 256 + threadIdx.x) * 8;
  float4 a = *(const float4*)(src + i);
  float4 b = *(const float4*)(src + i + 4);
  bf16x8 o;
  o[0] = (bf16_t)a.x; o[1] = (bf16_t)a.y; o[2] = (bf16_t)a.z; o[3] = (bf16_t)a.w;
  o[4] = (bf16_t)b.x; o[5] = (bf16_t)b.y; o[6] = (bf16_t)b.z; o[7] = (bf16_t)b.w;
  *(bf16x8*)(dst + i) = o;
}

// ---------------------------------------------------------------------------
// GEMM v4: Out = (X @ W^T + bias) * scale. Tile 64x128, BK=64, 3-stage LDS
// pipeline with raw-barrier async. XOR-swizzled LDS (16B chunks).
// omode 0: bf16 [bh][s][64]; 1: bf16 [bh][d][s]; 2: fp32 [m][512].
// ---------------------------------------------------------------------------
__device__ __forceinline__ void gemm_body64(
    const bf16_t* __restrict__ X, const bf16_t* __restrict__ Wm,
    const float* __restrict__ bias, void* __restrict__ Out,
    int omode, float scale) {
  __shared__ bf16_t Asm[3][64 * 64];
  __shared__ bf16_t Bsm[3][128 * 64];

  const int tid = threadIdx.x;
  const int w = tid >> 6;
  const int lane = tid & 63;
  const int quad = lane >> 4, l15 = lane & 15;
  const int l8 = lane >> 3;
  const int swcol = ((lane & 7) ^ l8) * 8;  // swizzled source col (elems)
  const int m0 = blockIdx.x * 64;
  const int n0 = blockIdx.y * 128;
  const int moff = (w & 1) * 32;
  const int noff = (w >> 1) * 64;

  f32x4 acc[2][4];
#pragma unroll
  for (int mb = 0; mb < 2; mb++)
#pragma unroll
    for (int nb = 0; nb < 4; nb++) { acc[mb][nb][0] = 0.f; acc[mb][nb][1] = 0.f; acc[mb][nb][2] = 0.f; acc[mb][nb][3] = 0.f; }

  // stage K-step ks into LDS buffer bufi (6 GLLs per thread: 4 B + 2 A)
  auto stage = [&](int ks, int bufi) {
    const int k0 = ks * 64;
#pragma unroll
    for (int j = 0; j < 4; j++) {
      const int row = j * 32 + w * 8 + l8;
      GLL(Wm + (size_t)(n0 + row) * DM + k0 + swcol, &Bsm[bufi][(j * 256 + w * 64) * 8]);
    }
#pragma unroll
    for (int j = 0; j < 2; j++) {
      const int row = j * 32 + w * 8 + l8;
      GLL(X + (size_t)(m0 + row) * DM + k0 + swcol, &Asm[bufi][(j * 256 + w * 64) * 8]);
    }
  };

  stage(0, 0);
  stage(1, 1);

  for (int ks = 0; ks < 8; ks++) {
    WAIT_BARRIER_V6();             // step-ks tile landed everywhere; buffer
                                   // (ks-1)%3 free for reuse
    const int tn = (ks + 2 < 8) ? ks + 2 : 7;   // dummy re-issue keeps counts uniform
    stage(tn, (ks + 2) % 3);
    const int p = ks % 3;

#pragma unroll
    for (int kd = 0; kd < 2; kd++) {
      const int fch = (((kd << 2) + quad) ^ (l15 & 7)) << 3;
      bf16x8 bfr[4];
#pragma unroll
      for (int nb = 0; nb < 4; nb++)
        bfr[nb] = *(const bf16x8*)&Bsm[p][(noff + nb * 16 + l15) * 64 + fch];
#pragma unroll
      for (int mb = 0; mb < 2; mb++) {
        bf16x8 a = *(const bf16x8*)&Asm[p][(moff + mb * 16 + l15) * 64 + fch];
#pragma unroll
        for (int nb = 0; nb < 4; nb++) acc[mb][nb] = MFMA16(a, bfr[nb], acc[mb][nb]);
      }
    }
  }

  // ---- epilogue ----
#pragma unroll
  for (int nb = 0; nb < 4; nb++) {
    const int n = n0 + noff + nb * 16 + l15;
    const float bn = bias[n];
    const int h = n >> 6, dd = n & 63;
#pragma unroll
    for (int mb = 0; mb < 2; mb++) {
      const int mbase = m0 + moff + mb * 16 + quad * 4;
      const int bb = mbase >> 12, s = mbase & 4095;
      if (omode == 0) {
#pragma unroll
        for (int r = 0; r < 4; r++) {
          const float val = (acc[mb][nb][r] + bn) * scale;
          ((bf16_t*)Out)[(size_t)((bb * NH + h) * SEQ + s + r) * HD + dd] = (bf16_t)val;
        }
      } else if (omode == 1) {
        bf16x4 pk;
#pragma unroll
        for (int r = 0; r < 4; r++) pk[r] = (bf16_t)(acc[mb][nb][r] + bn);
        *(bf16x4*)&((bf16_t*)Out)[(((size_t)(bb * NH + h) * HD + dd) << 12) + s] = pk;
      } else {
#pragma unroll
        for (int r = 0; r < 4; r++)
          ((float*)Out)[(size_t)(mbase + r) * DM + n] = acc[mb][nb][r] + bn;
      }
    }
  }
}

// Fused QKV projection (bf16 inputs). Grid (128,4,3).
__global__ __launch_bounds__(256, 2) void qkv_kernel(
    const bf16_t* __restrict__ Xall, const bf16_t* __restrict__ Wall,
    const float* __restrict__ bq, const float* __restrict__ bk,
    const float* __restrict__ bv, bf16_t* __restrict__ Qb,
    bf16_t* __restrict__ Kb, bf16_t* __restrict__ Vb, float qscale) {
  const int z = blockIdx.z;
  const bf16_t* X = Xall + (size_t)z * (M_ROWS * DM);
  const float* bias = (z == 0) ? bq : (z == 1) ? bk : bv;
  bf16_t* Out = (z == 0) ? Qb : (z == 1) ? Kb : Vb;
  gemm_body64(X, Wall + (size_t)z * DM * DM, bias, Out,
              (z == 2) ? 1 : 0, (z == 0) ? qscale : 1.0f);
}

// Output projection. Grid (128,4).
__global__ __launch_bounds__(256, 2) void oproj_kernel(
    const bf16_t* __restrict__ X, const bf16_t* __restrict__ Wm,
    const float* __restrict__ bias, float* __restrict__ Out) {
  gemm_body64(X, Wm, bias, Out, 2, 1.0f);
}

// ---------------------------------------------------------------------------
// Flash attention v9: 2 tiles (128 kk) per barrier phase.
// Evidence: v6-v8 all kept 64 barrier-phases and all landed at ~3620 cyc/tile
// while no pipe exceeded 42% busy -> per-phase overhead (barrier skew +
// post-barrier refill + in-order bubbles) dominates. Halve the phase count:
// per iteration j process tiles e=2j, o=2j+1 with ONE vmcnt(0)+s_barrier.
// Prologue stages tiles 0,1; iteration j stages e+2,o+2 into the buffer pair
// freed by the previous iteration (barrier-guaranteed). In-flight time of a
// stage = one full iteration >> L2 latency, so the vmcnt(0) is free.
// Compute order QK(e),QK(o),sm_pv(e),sm_pv(o): softmax(e) VALU overlaps
// QK(o) MFMA drain; softmax(o) overlaps PV(e) -- MFMA||VALU decoupling
// without cross-iteration ping-pong.
// Retained from v8: 2x2 wave-role split (wq 64q halves, wk 32kk halves),
// in-register P redistribution, XCD swizzle, cross-wave O/l reduction.
// Grid (512).
// ---------------------------------------------------------------------------
__global__ __launch_bounds__(256, 2) void attn_kernel(
    const bf16_t* __restrict__ Qb, const bf16_t* __restrict__ Kb,
    const bf16_t* __restrict__ Vb, const float* __restrict__ rel_pos,
    bf16_t* __restrict__ attn_out) {
  __shared__ bf16_t Kt[4][64 * 64];    // swizzled [kk][d], tile t -> buf t&3
  __shared__ bf16_t Vt[4][64 * 64];    // swizzled [d][kk]

  const int tid = threadIdx.x;
  const int w = tid >> 6;
  const int lane = tid & 63;
  const int quad = lane >> 4, l15 = lane & 15;
  const int wq = w >> 1, wk = w & 1;

  // XCD swizzle: 512 blocks, 8 XCDs -> 64 consecutive per XCD (bijective)
  const int lin = blockIdx.x;
  const int glob = (lin & 7) * 64 + (lin >> 3);
  const int bh = glob >> 5;        // 2 bh per XCD
  const int qb = glob & 31;
  const int b = bh >> 3, h = bh & 7;
  const int qlo = qb * 128 + wq * 64;  // wave's 64-q base

  const float rb0 = rel_pos[h * 5 + 0] * LOG2E;
  const float rb1 = rel_pos[h * 5 + 1] * LOG2E;
  const float rb2 = rel_pos[h * 5 + 2] * LOG2E;
  const float rb3 = rel_pos[h * 5 + 3] * LOG2E;
  const float rb4 = rel_pos[h * 5 + 4] * LOG2E;

  // Q fragments (B-operand): four q-groups of 16
  bf16x8 qf[4][2];
#pragma unroll
  for (int mb = 0; mb < 4; mb++)
#pragma unroll
    for (int kd = 0; kd < 2; kd++)
      qf[mb][kd] = *(const bf16x8*)(Qb + (size_t)(bh * SEQ + qlo + mb * 16 + l15) * HD + kd * 32 + 8 * quad);

  f32x4 o[4][4];
#pragma unroll
  for (int mb = 0; mb < 4; mb++)
#pragma unroll
    for (int db = 0; db < 4; db++) { o[mb][db][0] = 0.f; o[mb][db][1] = 0.f; o[mb][db][2] = 0.f; o[mb][db][3] = 0.f; }
  f32x4 l4[4];
#pragma unroll
  for (int mb = 0; mb < 4; mb++) { l4[mb][0] = 0.f; l4[mb][1] = 0.f; l4[mb][2] = 0.f; l4[mb][3] = 0.f; }

  bf16x8 ones;
#pragma unroll
  for (int i = 0; i < 8; i++) ones[i] = (bf16_t)1.0f;

  // --- staging addresses (swizzled): phys chunk = logical ^ (row&7)
  const int srow = (w << 4) + (lane >> 3);
  const int scol = (((lane & 7) ^ (lane >> 3)) << 3);
  const bf16_t* kg0 = Kb + ((size_t)(bh * SEQ + srow) << 6) + scol;
  const bf16_t* vg0 = Vb + (((size_t)(bh * HD + srow)) << 12) + scol;
  const int ldst = (w << 10);  // wave's LDS dest (elems)

  // --- fragment read bases (swizzled)
  const int sw = l15 & 7;
  const int kfo0 = (l15 << 6) + ((quad ^ sw) << 3);             // d-half 0
  const int kfo1 = (l15 << 6) + (((quad + 4) ^ sw) << 3);       // d-half 1
  // V fragment: logical kk-chunk = wk*4 + quad
  const int vfo = (l15 << 6) + ((((wk << 2) + quad) ^ sw) << 3);
  const int wk2 = wk << 1;     // row-block base for K reads (wk half)

  auto stage = [&](int t, int bufi) {
    GLL(kg0 + ((size_t)t << 12), &Kt[bufi][ldst]);
    GLL(kg0 + ((size_t)t << 12) + (8 << 6), &Kt[bufi][ldst + 512]);
    GLL(vg0 + (t << 6), &Vt[bufi][ldst]);
    GLL(vg0 + (t << 6) + (8 << 12), &Vt[bufi][ldst + 512]);
  };

  // QK^T for wave's 32-kk slice of tile tq (acc init folds bias const+shift)
  auto qk_tile = [&](int tq, f32x4 (&s)[4][2]) {
    const int klo = tq * 64 + wk * 32;
    float cini;
    if (klo >= qlo + 65)        cini = rb4 - SHIFT;
    else if (klo <= qlo - 33)   cini = rb0 - SHIFT;
    else                        cini = -SHIFT;
#pragma unroll
    for (int mb = 0; mb < 4; mb++)
#pragma unroll
      for (int kb = 0; kb < 2; kb++) { s[mb][kb][0] = cini; s[mb][kb][1] = cini; s[mb][kb][2] = cini; s[mb][kb][3] = cini; }
    const int pq = tq & 3;
    __builtin_amdgcn_s_setprio(1);
#pragma unroll
    for (int kb = 0; kb < 2; kb++) {
      bf16x8 kA0 = *(const bf16x8*)&Kt[pq][kfo0 + ((wk2 + kb) << 10)];
      bf16x8 kA1 = *(const bf16x8*)&Kt[pq][kfo1 + ((wk2 + kb) << 10)];
      s[0][kb] = MFMA16(kA0, qf[0][0], s[0][kb]);
      s[0][kb] = MFMA16(kA1, qf[0][1], s[0][kb]);
      s[1][kb] = MFMA16(kA0, qf[1][0], s[1][kb]);
      s[1][kb] = MFMA16(kA1, qf[1][1], s[1][kb]);
      s[2][kb] = MFMA16(kA0, qf[2][0], s[2][kb]);
      s[2][kb] = MFMA16(kA1, qf[2][1], s[2][kb]);
      s[3][kb] = MFMA16(kA0, qf[3][0], s[3][kb]);
      s[3][kb] = MFMA16(kA1, qf[3][1], s[3][kb]);
    }
    __builtin_amdgcn_s_setprio(0);
  };

  // softmax on wave's slice + l accumulation + partial PV
  auto sm_pv = [&](int t, f32x4 (&s)[4][2]) {
    const int klo = t * 64 + wk * 32;
    const bool nearband = !(klo >= qlo + 65) && !(klo <= qlo - 33);
    if (nearband) {
#pragma unroll
      for (int mb = 0; mb < 4; mb++) {
        const int qg = qlo + mb * 16 + l15;
#pragma unroll
        for (int kb = 0; kb < 2; kb++)
#pragma unroll
          for (int r = 0; r < 4; r++) {
            int dl = klo + kb * 16 + quad * 4 + r - qg;
            float bias = dl <= -2 ? rb0
                       : (dl >= 2 ? rb4
                       : (dl == -1 ? rb1 : (dl == 0 ? rb2 : rb3)));
            s[mb][kb][r] += bias;
          }
      }
    }

    // p = exp2(s) -> bf16 pack -> in-register redistribution (one frag/mb)
    bf16x8 pf[4];
#pragma unroll
    for (int mb = 0; mb < 4; mb++) {
      unsigned int u[2][2];
#pragma unroll
      for (int kb = 0; kb < 2; kb++) {
        bf16x2 p0, p1;
        p0[0] = (bf16_t)__builtin_amdgcn_exp2f(s[mb][kb][0]);
        p0[1] = (bf16_t)__builtin_amdgcn_exp2f(s[mb][kb][1]);
        p1[0] = (bf16_t)__builtin_amdgcn_exp2f(s[mb][kb][2]);
        p1[1] = (bf16_t)__builtin_amdgcn_exp2f(s[mb][kb][3]);
        u[kb][0] = __builtin_bit_cast(unsigned int, p0);
        u[kb][1] = __builtin_bit_cast(unsigned int, p1);
      }
      unsigned int a0 = u[0][0], b0 = u[1][0];
      unsigned int a1 = u[0][1], b1 = u[1][1];
      asm("v_permlane32_swap_b32 %0, %1" : "+v"(a0), "+v"(b0));
      asm("v_permlane32_swap_b32 %0, %1" : "+v"(a1), "+v"(b1));
      asm("v_permlane16_swap_b32 %0, %1" : "+v"(a0), "+v"(b0));
      asm("v_permlane16_swap_b32 %0, %1" : "+v"(a1), "+v"(b1));
      u32x4 pk; pk[0] = a0; pk[1] = a1; pk[2] = b0; pk[3] = b1;
      pf[mb] = __builtin_bit_cast(bf16x8, pk);
    }

    const int p = t & 3;
    __builtin_amdgcn_s_setprio(1);
    l4[0] = MFMA16(ones, pf[0], l4[0]);
    l4[1] = MFMA16(ones, pf[1], l4[1]);
    l4[2] = MFMA16(ones, pf[2], l4[2]);
    l4[3] = MFMA16(ones, pf[3], l4[3]);
#pragma unroll
    for (int db = 0; db < 4; db++) {
      bf16x8 vA = *(const bf16x8*)&Vt[p][vfo + (db << 10)];
      o[0][db] = MFMA16(vA, pf[0], o[0][db]);
      o[1][db] = MFMA16(vA, pf[1], o[1][db]);
      o[2][db] = MFMA16(vA, pf[2], o[2][db]);
      o[3][db] = MFMA16(vA, pf[3], o[3][db]);
    }
    __builtin_amdgcn_s_setprio(0);
  };

  // prologue: stage tiles 0,1 (8 GLLs in flight)
  stage(0, 0);
  stage(1, 1);

  f32x4 sA[4][2], sB[4][2];

  for (int j = 0; j < 32; j++) {
    const int e = 2 * j, o2 = 2 * j + 1;
    WAIT_BARRIER_V0();             // tiles e,o landed; prev pair's buffers free
    const int ta = (e + 2 < 64) ? e + 2 : 63;   // dummy clamp keeps counts uniform
    const int tb = (o2 + 2 < 64) ? o2 + 2 : 63;
    stage(ta, (e + 2) & 3);        // into buffer freed by tile e-2
    stage(tb, (o2 + 2) & 3);       // into buffer freed by tile o-2
    qk_tile(e, sA);
    qk_tile(o2, sB);
    sm_pv(e, sA);                  // softmax(e) VALU overlaps QK(o) MFMA drain
    sm_pv(o2, sB);                 // softmax(o) overlaps PV(e) MFMA drain
  }

  // ---- cross-wave (wk) reduction of partial O,l via LDS, then epilogue ----
  asm volatile("s_waitcnt vmcnt(0)" ::: "memory");  // dummy stages landed
  __syncthreads();
  float* Ored = (float*)&Kt[0][0];   // 2 x 16KB (per wq)
  float* lred = (float*)&Vt[0][0];   // 2 x 256B
  if (wk) {
#pragma unroll
    for (int mb = 0; mb < 4; mb++) {
      lred[(wq << 6) + (mb << 4) + l15] = l4[mb][0];
#pragma unroll
      for (int db = 0; db < 4; db++) {
        const int ch = ((db << 2) | quad) ^ sw;
        *(f32x4*)&Ored[(wq << 12) + ((mb * 16 + l15) << 6) + (ch << 2)] = o[mb][db];
      }
    }
  }
  __syncthreads();
  if (!wk) {
#pragma unroll
    for (int mb = 0; mb < 4; mb++) {
      float lsum = l4[mb][0] + lred[(wq << 6) + (mb << 4) + l15];
      const float inv = 1.0f / lsum;
      const int qg = qlo + mb * 16 + l15;
#pragma unroll
      for (int db = 0; db < 4; db++) {
        const int ch = ((db << 2) | quad) ^ sw;
        const f32x4 part = *(const f32x4*)&Ored[(wq << 12) + ((mb * 16 + l15) << 6) + (ch << 2)];
        bf16x4 pk;
#pragma unroll
        for (int r = 0; r < 4; r++) pk[r] = (bf16_t)((o[mb][db][r] + part[r]) * inv);
        *(bf16x4*)(attn_out + (size_t)(b * SEQ + qg) * DM + h * HD + db * 16 + quad * 4) = pk;
      }
    }
  }
}

// ---------------------------------------------------------------------------
extern "C" void kernel_launch(void* const* d_in, const int* in_sizes, int n_in,
                              void* d_out, int out_size, void* d_ws, size_t ws_size,
                              hipStream_t stream) {
  const float* q   = (const float*)d_in[0];
  const float* k   = (const float*)d_in[1];
  const float* v   = (const float*)d_in[2];
  const float* Wq  = (const float*)d_in[3];
  const float* bq  = (const float*)d_in[4];
  const float* Wk  = (const float*)d_in[5];
  const float* bk  = (const float*)d_in[6];
  const float* Wv  = (const float*)d_in[7];
  const float* bv  = (const float*)d_in[8];
  const float* Wo  = (const float*)d_in[9];
  const float* bo  = (const float*)d_in[10];
  const float* rel = (const float*)d_in[11];

  char* ws = (char*)d_ws;
  bf16_t* Wbf  = (bf16_t*)ws;                               // 2MB (4 matrices)
  bf16_t* Xb   = (bf16_t*)(ws + (size_t)(2  << 20));        // 24MB bf16 q,k,v
  bf16_t* Qbuf = (bf16_t*)(ws + (size_t)(26 << 20));        // 8MB [bh][s][64]
  bf16_t* Kbuf = (bf16_t*)(ws + (size_t)(34 << 20));        // 8MB [bh][s][64]
  bf16_t* Vbuf = (bf16_t*)(ws + (size_t)(42 << 20));        // 8MB [bh][d][s]
  bf16_t* Abuf = (bf16_t*)(ws + (size_t)(2  << 20));        // alias Xb (dead after qkv)

  cvt_w_kernel<<<dim3(256, 4), 256, 0, stream>>>(Wq, Wk, Wv, Wo, Wbf);
  cvt_x_kernel<<<dim3(2048, 3), 256, 0, stream>>>(q, k, v, Xb);

  const float qscale = LOG2E / 8.0f;  // fold 1/sqrt(64) + exp2 domain
  qkv_kernel<<<dim3(128, 4, 3), 256, 0, stream>>>(
      Xb, Wbf, bq, bk, bv, Qbuf, Kbuf, Vbuf, qscale);

  attn_kernel<<<512, 256, 0, stream>>>(Qbuf, Kbuf, Vbuf, rel, Abuf);

  oproj_kernel<<<dim3(128, 4), 256, 0, stream>>>(Abuf, Wbf + 3 * DM * DM, bo, (float*)d_out);
}